// Round 3
// baseline (191.468 us; speedup 1.0000x reference)
//
#include <hip/hip_runtime.h>
#include <hip/hip_bf16.h>
#include <math.h>

// Problem constants
#define BB 8
#define NN 80
#define DD 128
#define NNODE (BB*NN)            // 640
#define ND (NNODE*DD)            // 81920
#define NA (BB*NN*NN)            // 51200
#define NW ((size_t)NNODE*DD*DD) // 10,485,760

typedef float f4 __attribute__((ext_vector_type(4)));

__device__ __forceinline__ float pred_nl(float v) {
    const float PHI_C = 1.61803398875f;
    const float PREDS = 1.8477590650225735f; // sqrt(2 + sqrt(2))
    float raw = v - tanhf(v) * PHI_C;
    return tanhf(raw) * PREDS;
}

// ---------------------------------------------------------------------------
// K1: fused GEMV + bulk weight/momentum update. blockIdx.x = node*3 + mat.
// For every f4 column-group EXCEPT the <=2 groups containing the gaussian
// window center: g_mask underflows to exactly 0.0f in f32 (diff>=2 =>
// exp(-<=-200) < 2^-149), so Mn = 0.42*M and Wn = W + 0.001*Mn exactly.
// Center groups are stashed to ws (and their stores skipped); K2 finishes
// them with the exact reference formula once coef is known.
// ---------------------------------------------------------------------------
__global__ __launch_bounds__(256) void k_fused(
    const float* __restrict__ W1, const float* __restrict__ W2,
    const float* __restrict__ W3, const float* __restrict__ M1,
    const float* __restrict__ M2, const float* __restrict__ M3,
    const float* __restrict__ state, const float* __restrict__ stepc,
    float* __restrict__ pred, float* __restrict__ q_ws, float* __restrict__ k_ws,
    float* __restrict__ W1n, float* __restrict__ W2n, float* __restrict__ W3n,
    float* __restrict__ M1n, float* __restrict__ M2n, float* __restrict__ M3n,
    f4* __restrict__ stW4, f4* __restrict__ stM4, int do_stash)
{
    int bid  = blockIdx.x;
    int node = bid / 3;
    int mat  = bid - node * 3;
    const float *W, *M; float *Wn, *Mn;
    if (mat == 0)      { W = W1; M = M1; Wn = W1n; Mn = M1n; }
    else if (mat == 1) { W = W2; M = M2; Wn = W2n; Mn = M2n; }
    else               { W = W3; M = M3; Wn = W3n; Mn = M3n; }
    size_t base4 = (size_t)node * 4096;            // f4 offset of this node's matrix
    const f4* Wv = (const f4*)W + base4;
    const f4* Mv = (const f4*)M + base4;
    f4* Wnv = (f4*)Wn + base4;
    f4* Mnv = (f4*)Mn + base4;

    __shared__ __align__(16) float sv[DD];
    __shared__ f4 red[256];
    int t = threadIdx.x;
    if (t < DD) sv[t] = state[(size_t)node * DD + t];
    __syncthreads();

    // gaussian-center column groups (uniform across grid)
    float counter = stepc[0] + 1.0f;
    float center  = fmodf(counter * 1.5f, 128.0f);
    int c0 = (int)floorf(center);
    int g0 = ((c0 - 1) & 127) >> 2;
    int g1 = ((c0 + 2) & 127) >> 2;

    int jj = t >> 5;   // row residue class (0..7)
    int kq = t & 31;   // f4 column group
    int sg = -1;
    if (kq == g0) sg = 0;
    else if (kq == g1) sg = 1;

    f4 acc = (f4)0.0f;
    #pragma unroll
    for (int r = 0; r < 16; ++r) {
        int j = jj + r * 8;
        f4 w = Wv[j * 32 + kq];
        f4 m = Mv[j * 32 + kq];
        float sj = sv[j];
        acc.x = fmaf(sj, w.x, acc.x);
        acc.y = fmaf(sj, w.y, acc.y);
        acc.z = fmaf(sj, w.z, acc.z);
        acc.w = fmaf(sj, w.w, acc.w);
        if (sg < 0) {
            f4 mn = 0.42f * m;
            f4 wn = w + 0.001f * mn;
            Mnv[j * 32 + kq] = mn;
            Wnv[j * 32 + kq] = wn;
        } else if (do_stash) {
            size_t si = ((size_t)(mat * NNODE + node) * 2 + sg) * DD + j;
            stW4[si] = w;
            stM4[si] = m;
        }
    }
    red[t] = acc;
    __syncthreads();
    if (t < 32) {
        f4 r = red[t];
        #pragma unroll
        for (int p = 1; p < 8; ++p) r += red[p * 32 + t];
        if (mat == 0) {
            f4 pz;
            pz.x = pred_nl(r.x); pz.y = pred_nl(r.y);
            pz.z = pred_nl(r.z); pz.w = pred_nl(r.w);
            ((f4*)(pred + (size_t)node * DD))[t] = pz;
        } else if (mat == 1) {
            ((f4*)(k_ws + (size_t)node * DD))[t] = r;
        } else {
            ((f4*)(q_ws + (size_t)node * DD))[t] = r;
        }
    }
}

// ---------------------------------------------------------------------------
// K2: routing + softmax chain -> coef (in-register), then exact update of the
// center column groups (full-f4 stores, no partial lines). One block per node.
// ---------------------------------------------------------------------------
__global__ __launch_bounds__(128) void k_route_fix(
    const float* __restrict__ q_ws, const float* __restrict__ k_ws,
    const float* __restrict__ A_in, const float* __restrict__ outp,
    const float* __restrict__ eye, const float* __restrict__ stomach,
    const float* __restrict__ pred, const float* __restrict__ Ebase,
    const float* __restrict__ stepc, const float* __restrict__ state,
    const float* __restrict__ W1, const float* __restrict__ W2,
    const float* __restrict__ W3, const float* __restrict__ M1,
    const float* __restrict__ M2, const float* __restrict__ M3,
    const f4* __restrict__ stW4, const f4* __restrict__ stM4, int use_stash,
    float* __restrict__ target, float* __restrict__ Anew,
    float* __restrict__ EbOut,
    float* __restrict__ W1n, float* __restrict__ W2n, float* __restrict__ W3n,
    float* __restrict__ M1n, float* __restrict__ M2n, float* __restrict__ M3n,
    float* __restrict__ counter_out)
{
    int node = blockIdx.x;        // b*NN + n
    int b = node / NN;
    int n = node - b * NN;
    int t = threadIdx.x;
    int lane = t & 63;
    int wv = t >> 6;              // wave id (0 or 1)

    __shared__ __align__(16) float q_l[DD];
    __shared__ float raw[NN];
    __shared__ float a_l[NN];
    __shared__ int   idx5[5];
    __shared__ float p5[5];
    __shared__ float redbuf[2];

    q_l[t] = q_ws[(size_t)node * DD + t];
    __syncthreads();

    // raw_A[n,m] = dot(q_n, k_m) / sqrt(D)
    for (int m = wv; m < NN; m += 2) {
        const float* K = k_ws + (size_t)(b * NN + m) * DD;
        float p = q_l[lane] * K[lane] + q_l[lane + 64] * K[lane + 64];
        #pragma unroll
        for (int off = 32; off > 0; off >>= 1) p += __shfl_xor(p, off);
        if (lane == 0) raw[m] = p * 0.08838834764831845f; // 1/sqrt(128)
    }
    __syncthreads();

    // top-5 + softmax (serial, tiny; lax.top_k tie semantics: strict >)
    if (t == 0) {
        float vals[5]; int ids[5];
        for (int p = 0; p < 5; ++p) {
            float best = -INFINITY; int bi = 0;
            for (int m = 0; m < NN; ++m) {
                bool skip = false;
                for (int q = 0; q < p; ++q) if (ids[q] == m) skip = true;
                if (skip) continue;
                float v = raw[m];
                if (v > best) { best = v; bi = m; }
            }
            vals[p] = best; ids[p] = bi;
        }
        float mx = vals[0], s = 0.f, e[5];
        for (int p = 0; p < 5; ++p) { e[p] = expf(vals[p] - mx); s += e[p]; }
        for (int p = 0; p < 5; ++p) { p5[p] = e[p] / s; idx5[p] = ids[p]; }
    }
    __syncthreads();

    // A_new = 0.99*A + 0.01*P; rows 0,1 zeroed
    if (t < NN) {
        float P = 0.f;
        #pragma unroll
        for (int q = 0; q < 5; ++q) if (idx5[q] == t) P = p5[q];
        float a = A_in[(size_t)b * NN * NN + (size_t)n * NN + t] * 0.99f + P * 0.01f;
        if (n < 2) a = 0.f;
        a_l[t] = a;
        Anew[(size_t)b * NN * NN + (size_t)n * NN + t] = a;
    }
    __syncthreads();

    // target = A_new-weighted message aggregation (rows 0/1 -> env)
    float tg = 0.f;
    for (int m = 0; m < NN; ++m)
        tg = fmaf(a_l[m], outp[(size_t)(b * NN + m) * DD + t], tg);
    if (n == 0) tg = eye[b * DD + t];
    else if (n == 1) tg = stomach[b * DD + t];

    float err = pred[(size_t)node * DD + t] - tg;

    // softmax over D=128 (2 waves)
    float v = err;
    #pragma unroll
    for (int off = 32; off > 0; off >>= 1) v = fmaxf(v, __shfl_xor(v, off));
    if (lane == 0) redbuf[wv] = v;
    __syncthreads();
    float mx = fmaxf(redbuf[0], redbuf[1]);
    __syncthreads();          // before redbuf reuse
    float e = expf(err - mx);
    v = e;
    #pragma unroll
    for (int off = 32; off > 0; off >>= 1) v += __shfl_xor(v, off);
    if (lane == 0) redbuf[wv] = v;
    __syncthreads();
    float Ecur = e / (redbuf[0] + redbuf[1]);

    float ebin = Ebase[(size_t)node * DD + t];
    float eb0  = (ebin == 0.f) ? Ecur : ebin;
    float EbV  = 0.5f * eb0 + 0.5f * Ecur;
    float adv  = Ecur - EbV;
    float R    = -(adv * (1.0f / sqrtf(adv * adv + 1e-8f))); // rms_norm over size-1 axis
    float plast = 1.f - R;
    float maskp = (EbV > 0.f) ? 1.f : 0.f;
    float coef  = -plast * err * maskp;   // hebb[i][j] = coef_i * state_j

    target[(size_t)node * DD + t] = tg;
    EbOut [(size_t)node * DD + t] = EbV;
    if (node == 0 && t == 0) counter_out[0] = stepc[0] + 1.0f;

    // ---- fix phase: exact update of center column groups, row i = t ----
    float counter = stepc[0] + 1.0f;
    float center  = fmodf(counter * 1.5f, 128.0f);
    int c0 = (int)floorf(center);
    int g0 = ((c0 - 1) & 127) >> 2;
    int g1 = ((c0 + 2) & 127) >> 2;
    int grp[2] = {g0, g1};
    int nslot = (g1 == g0) ? 1 : 2;
    int i = t;
    for (int sg = 0; sg < nslot; ++sg) {
        int g = grp[sg];
        f4 w[3], m[3];
        if (use_stash) {
            #pragma unroll
            for (int mat = 0; mat < 3; ++mat) {
                size_t si = ((size_t)(mat * NNODE + node) * 2 + sg) * DD + i;
                w[mat] = stW4[si];
                m[mat] = stM4[si];
            }
        } else {
            size_t bi = (size_t)node * 4096 + (size_t)i * 32 + g;
            w[0] = ((const f4*)W1)[bi]; w[1] = ((const f4*)W2)[bi]; w[2] = ((const f4*)W3)[bi];
            m[0] = ((const f4*)M1)[bi]; m[1] = ((const f4*)M2)[bi]; m[2] = ((const f4*)M3)[bi];
        }
        f4 wn[3], mn[3];
        #pragma unroll
        for (int d = 0; d < 4; ++d) {
            int c = 4 * g + d;
            float diff = fabsf((float)c - center);
            diff = fminf(diff, 128.0f - diff);
            float gm = expf(-diff * diff / 0.020001f);   // 2*0.1^2 + 1e-6
            float hebb = coef * state[(size_t)node * DD + c];
            #pragma unroll
            for (int mat = 0; mat < 3; ++mat) {
                int prev = (mat == 0) ? 2 : mat - 1;     // grad1<-W3, grad2<-W1, grad3<-W2
                float grad = (hebb + 0.01f * w[prev][d] - 0.01f * w[mat][d]) * gm;
                float mval = 0.42f * m[mat][d] + 0.58f * grad;
                mn[mat][d] = mval;
                wn[mat][d] = w[mat][d] + 0.001f * mval;
            }
        }
        size_t bo = (size_t)node * 4096 + (size_t)i * 32 + g;
        ((f4*)W1n)[bo] = wn[0]; ((f4*)W2n)[bo] = wn[1]; ((f4*)W3n)[bo] = wn[2];
        ((f4*)M1n)[bo] = mn[0]; ((f4*)M2n)[bo] = mn[1]; ((f4*)M3n)[bo] = mn[2];
    }
}

// ---------------------------------------------------------------------------
extern "C" void kernel_launch(void* const* d_in, const int* in_sizes, int n_in,
                              void* d_out, int out_size, void* d_ws, size_t ws_size,
                              hipStream_t stream) {
    const float* W1     = (const float*)d_in[0];
    const float* W2     = (const float*)d_in[1];
    const float* W3     = (const float*)d_in[2];
    const float* M1     = (const float*)d_in[3];
    const float* M2     = (const float*)d_in[4];
    const float* M3     = (const float*)d_in[5];
    const float* Ebase  = (const float*)d_in[6];
    const float* state  = (const float*)d_in[7];
    const float* outp   = (const float*)d_in[8];
    const float* A_in   = (const float*)d_in[9];
    const float* stepc  = (const float*)d_in[10];
    const float* eye    = (const float*)d_in[11];
    const float* stom   = (const float*)d_in[12];

    float* out = (float*)d_out;
    float* pred    = out;
    float* target  = out + ND;
    float* Anew    = out + 2 * ND;
    float* EbOut   = out + 2 * ND + NA;
    float* W1n     = out + 3 * ND + NA;
    float* W2n     = W1n + NW;
    float* W3n     = W2n + NW;
    float* M1n     = W3n + NW;
    float* M2n     = M1n + NW;
    float* M3n     = M2n + NW;
    float* counter_out = M3n + NW;       // final scalar

    float* ws = (float*)d_ws;
    float* q_ws = ws;
    float* k_ws = ws + ND;
    // center-group stash: [3 mats][640 nodes][2 slots][128 rows] of f4
    f4* stW4 = (f4*)(ws + 2 * ND);
    f4* stM4 = stW4 + (size_t)3 * NNODE * 2 * DD;
    size_t need = (size_t)2 * ND * 4 + (size_t)2 * 3 * NNODE * 2 * DD * 16;
    int use_stash = (ws_size >= need) ? 1 : 0;

    k_fused<<<NNODE * 3, 256, 0, stream>>>(
        W1, W2, W3, M1, M2, M3, state, stepc,
        pred, q_ws, k_ws, W1n, W2n, W3n, M1n, M2n, M3n,
        stW4, stM4, use_stash);
    k_route_fix<<<NNODE, 128, 0, stream>>>(
        q_ws, k_ws, A_in, outp, eye, stom, pred, Ebase, stepc, state,
        W1, W2, W3, M1, M2, M3, stW4, stM4, use_stash,
        target, Anew, EbOut, W1n, W2n, W3n, M1n, M2n, M3n, counter_out);
}

// Round 4
// 159.957 us; speedup vs baseline: 1.1970x; 1.1970x over previous
//
#include <hip/hip_runtime.h>
#include <hip/hip_bf16.h>
#include <math.h>

// Problem constants
#define BB 8
#define NN 80
#define DD 128
#define NNODE (BB*NN)            // 640
#define ND (NNODE*DD)            // 81920
#define NA (BB*NN*NN)            // 51200
#define NW ((size_t)NNODE*DD*DD) // 10,485,760

typedef float f4 __attribute__((ext_vector_type(4)));

__device__ __forceinline__ float pred_nl(float v) {
    const float PHI_C = 1.61803398875f;
    const float PREDS = 1.8477590650225735f; // sqrt(2 + sqrt(2))
    float raw = v - tanhf(v) * PHI_C;
    return tanhf(raw) * PREDS;
}

// ---------------------------------------------------------------------------
// K1: fused GEMV + bulk update, one pass over W+M. blockIdx.x = node*3+mat.
// g_mask underflows to exactly 0.0f for all columns except the <=2 f4 groups
// around the gaussian center, so the update there is Mn=0.42*M,
// Wn=W+0.001*Mn (coef-independent). We store that bulk formula for ALL
// column groups (no divergence, no write holes); K2 then overwrites the
// center groups with the exact reference formula.
// MLP: 8-row batches, 16 loads issued back-to-back before compute+store.
// ---------------------------------------------------------------------------
__global__ __launch_bounds__(256) void k_fused(
    const float* __restrict__ W1, const float* __restrict__ W2,
    const float* __restrict__ W3, const float* __restrict__ M1,
    const float* __restrict__ M2, const float* __restrict__ M3,
    const float* __restrict__ state,
    float* __restrict__ pred, float* __restrict__ q_ws, float* __restrict__ k_ws,
    float* __restrict__ W1n, float* __restrict__ W2n, float* __restrict__ W3n,
    float* __restrict__ M1n, float* __restrict__ M2n, float* __restrict__ M3n)
{
    int bid  = blockIdx.x;
    int node = bid / 3;
    int mat  = bid - node * 3;
    const float *W, *M; float *Wn, *Mn;
    if (mat == 0)      { W = W1; M = M1; Wn = W1n; Mn = M1n; }
    else if (mat == 1) { W = W2; M = M2; Wn = W2n; Mn = M2n; }
    else               { W = W3; M = M3; Wn = W3n; Mn = M3n; }
    size_t base4 = (size_t)node * 4096;
    const f4* Wv = (const f4*)W + base4;
    const f4* Mv = (const f4*)M + base4;
    f4* Wnv = (f4*)Wn + base4;
    f4* Mnv = (f4*)Mn + base4;

    __shared__ __align__(16) float sv[DD];
    __shared__ f4 red[256];
    int t = threadIdx.x;
    if (t < DD) sv[t] = state[(size_t)node * DD + t];
    __syncthreads();

    int jj = t >> 5;   // row residue class (0..7)
    int kq = t & 31;   // f4 column group

    f4 acc = (f4)0.0f;
    #pragma unroll
    for (int half = 0; half < 2; ++half) {
        f4 w[8], m[8];
        // issue all 16 loads back-to-back (MLP)
        #pragma unroll
        for (int u = 0; u < 8; ++u) {
            int j = jj + (half * 8 + u) * 8;
            w[u] = Wv[j * 32 + kq];
            m[u] = Mv[j * 32 + kq];
        }
        #pragma unroll
        for (int u = 0; u < 8; ++u) {
            int j = jj + (half * 8 + u) * 8;
            float sj = sv[j];
            acc.x = fmaf(sj, w[u].x, acc.x);
            acc.y = fmaf(sj, w[u].y, acc.y);
            acc.z = fmaf(sj, w[u].z, acc.z);
            acc.w = fmaf(sj, w[u].w, acc.w);
            f4 mn = 0.42f * m[u];
            f4 wn = w[u] + 0.001f * mn;
            __builtin_nontemporal_store(mn, Mnv + j * 32 + kq);
            __builtin_nontemporal_store(wn, Wnv + j * 32 + kq);
        }
    }
    red[t] = acc;
    __syncthreads();
    if (t < 32) {
        f4 r = red[t];
        #pragma unroll
        for (int p = 1; p < 8; ++p) r += red[p * 32 + t];
        if (mat == 0) {
            f4 pz;
            pz.x = pred_nl(r.x); pz.y = pred_nl(r.y);
            pz.z = pred_nl(r.z); pz.w = pred_nl(r.w);
            ((f4*)(pred + (size_t)node * DD))[t] = pz;
        } else if (mat == 1) {
            ((f4*)(k_ws + (size_t)node * DD))[t] = r;
        } else {
            ((f4*)(q_ws + (size_t)node * DD))[t] = r;
        }
    }
}

// ---------------------------------------------------------------------------
// K2: routing + softmax chain -> coef (in-register), then exact update of the
// center column groups (reads W/M directly, full-f4 stores overwrite K1's
// bulk values there). One block of 128 per node; t = matrix row i.
// ---------------------------------------------------------------------------
__global__ __launch_bounds__(128) void k_route_fix(
    const float* __restrict__ q_ws, const float* __restrict__ k_ws,
    const float* __restrict__ A_in, const float* __restrict__ outp,
    const float* __restrict__ eye, const float* __restrict__ stomach,
    const float* __restrict__ pred, const float* __restrict__ Ebase,
    const float* __restrict__ stepc, const float* __restrict__ state,
    const float* __restrict__ W1, const float* __restrict__ W2,
    const float* __restrict__ W3, const float* __restrict__ M1,
    const float* __restrict__ M2, const float* __restrict__ M3,
    float* __restrict__ target, float* __restrict__ Anew,
    float* __restrict__ EbOut,
    float* __restrict__ W1n, float* __restrict__ W2n, float* __restrict__ W3n,
    float* __restrict__ M1n, float* __restrict__ M2n, float* __restrict__ M3n,
    float* __restrict__ counter_out)
{
    int node = blockIdx.x;        // b*NN + n
    int b = node / NN;
    int n = node - b * NN;
    int t = threadIdx.x;
    int lane = t & 63;
    int wv = t >> 6;              // wave id (0 or 1)

    __shared__ __align__(16) float q_l[DD];
    __shared__ float raw[NN];
    __shared__ float a_l[NN];
    __shared__ int   idx5[5];
    __shared__ float p5[5];
    __shared__ float redbuf[2];

    // issue the center-group W/M loads EARLY so their latency hides under
    // the routing/softmax phase.
    float counter = stepc[0] + 1.0f;
    float center  = fmodf(counter * 1.5f, 128.0f);
    int c0 = (int)floorf(center);
    int g0 = ((c0 - 1) & 127) >> 2;
    int g1 = ((c0 + 2) & 127) >> 2;
    size_t rb = (size_t)node * 4096 + (size_t)t * 32;
    f4 wA[3], mA[3], wB[3], mB[3];
    {
        const f4* Ws0 = (const f4*)W1; const f4* Ws1 = (const f4*)W2; const f4* Ws2 = (const f4*)W3;
        const f4* Ms0 = (const f4*)M1; const f4* Ms1 = (const f4*)M2; const f4* Ms2 = (const f4*)M3;
        wA[0] = Ws0[rb + g0]; wA[1] = Ws1[rb + g0]; wA[2] = Ws2[rb + g0];
        mA[0] = Ms0[rb + g0]; mA[1] = Ms1[rb + g0]; mA[2] = Ms2[rb + g0];
        wB[0] = Ws0[rb + g1]; wB[1] = Ws1[rb + g1]; wB[2] = Ws2[rb + g1];
        mB[0] = Ms0[rb + g1]; mB[1] = Ms1[rb + g1]; mB[2] = Ms2[rb + g1];
    }

    q_l[t] = q_ws[(size_t)node * DD + t];
    __syncthreads();

    // raw_A[n,m] = dot(q_n, k_m) / sqrt(D)
    for (int m = wv; m < NN; m += 2) {
        const float* K = k_ws + (size_t)(b * NN + m) * DD;
        float p = q_l[lane] * K[lane] + q_l[lane + 64] * K[lane + 64];
        #pragma unroll
        for (int off = 32; off > 0; off >>= 1) p += __shfl_xor(p, off);
        if (lane == 0) raw[m] = p * 0.08838834764831845f; // 1/sqrt(128)
    }
    __syncthreads();

    // top-5 + softmax (serial, tiny; lax.top_k tie semantics: strict >)
    if (t == 0) {
        float vals[5]; int ids[5];
        for (int p = 0; p < 5; ++p) {
            float best = -INFINITY; int bi = 0;
            for (int m = 0; m < NN; ++m) {
                bool skip = false;
                for (int q = 0; q < p; ++q) if (ids[q] == m) skip = true;
                if (skip) continue;
                float v = raw[m];
                if (v > best) { best = v; bi = m; }
            }
            vals[p] = best; ids[p] = bi;
        }
        float mx = vals[0], s = 0.f, e[5];
        for (int p = 0; p < 5; ++p) { e[p] = expf(vals[p] - mx); s += e[p]; }
        for (int p = 0; p < 5; ++p) { p5[p] = e[p] / s; idx5[p] = ids[p]; }
    }
    __syncthreads();

    // A_new = 0.99*A + 0.01*P; rows 0,1 zeroed
    if (t < NN) {
        float P = 0.f;
        #pragma unroll
        for (int q = 0; q < 5; ++q) if (idx5[q] == t) P = p5[q];
        float a = A_in[(size_t)b * NN * NN + (size_t)n * NN + t] * 0.99f + P * 0.01f;
        if (n < 2) a = 0.f;
        a_l[t] = a;
        Anew[(size_t)b * NN * NN + (size_t)n * NN + t] = a;
    }
    __syncthreads();

    // target = A_new-weighted message aggregation (rows 0/1 -> env)
    float tg = 0.f;
    for (int m = 0; m < NN; ++m)
        tg = fmaf(a_l[m], outp[(size_t)(b * NN + m) * DD + t], tg);
    if (n == 0) tg = eye[b * DD + t];
    else if (n == 1) tg = stomach[b * DD + t];

    float err = pred[(size_t)node * DD + t] - tg;

    // softmax over D=128 (2 waves)
    float v = err;
    #pragma unroll
    for (int off = 32; off > 0; off >>= 1) v = fmaxf(v, __shfl_xor(v, off));
    if (lane == 0) redbuf[wv] = v;
    __syncthreads();
    float mx = fmaxf(redbuf[0], redbuf[1]);
    __syncthreads();          // before redbuf reuse
    float e = expf(err - mx);
    v = e;
    #pragma unroll
    for (int off = 32; off > 0; off >>= 1) v += __shfl_xor(v, off);
    if (lane == 0) redbuf[wv] = v;
    __syncthreads();
    float Ecur = e / (redbuf[0] + redbuf[1]);

    float ebin = Ebase[(size_t)node * DD + t];
    float eb0  = (ebin == 0.f) ? Ecur : ebin;
    float EbV  = 0.5f * eb0 + 0.5f * Ecur;
    float adv  = Ecur - EbV;
    float R    = -(adv * (1.0f / sqrtf(adv * adv + 1e-8f))); // rms_norm over size-1 axis
    float plast = 1.f - R;
    float maskp = (EbV > 0.f) ? 1.f : 0.f;
    float coef  = -plast * err * maskp;   // hebb[i][j] = coef_i * state_j

    target[(size_t)node * DD + t] = tg;
    EbOut [(size_t)node * DD + t] = EbV;
    if (node == 0 && t == 0) counter_out[0] = stepc[0] + 1.0f;

    // ---- fix phase: exact update of center column groups, row i = t ----
    int nslot = (g1 == g0) ? 1 : 2;
    for (int sg = 0; sg < nslot; ++sg) {
        int g = (sg == 0) ? g0 : g1;
        f4 *wp = (sg == 0) ? wA : wB;
        f4 *mp = (sg == 0) ? mA : mB;
        f4 wn[3], mn[3];
        #pragma unroll
        for (int d = 0; d < 4; ++d) {
            int c = 4 * g + d;
            float diff = fabsf((float)c - center);
            diff = fminf(diff, 128.0f - diff);
            float gm = expf(-diff * diff / 0.020001f);   // 2*0.1^2 + 1e-6
            float hebb = coef * state[(size_t)node * DD + c];
            #pragma unroll
            for (int mat = 0; mat < 3; ++mat) {
                int prev = (mat == 0) ? 2 : mat - 1;     // grad1<-W3, grad2<-W1, grad3<-W2
                float grad = (hebb + 0.01f * wp[prev][d] - 0.01f * wp[mat][d]) * gm;
                float mval = 0.42f * mp[mat][d] + 0.58f * grad;
                mn[mat][d] = mval;
                wn[mat][d] = wp[mat][d] + 0.001f * mval;
            }
        }
        size_t bo = rb + g;
        ((f4*)W1n)[bo] = wn[0]; ((f4*)W2n)[bo] = wn[1]; ((f4*)W3n)[bo] = wn[2];
        ((f4*)M1n)[bo] = mn[0]; ((f4*)M2n)[bo] = mn[1]; ((f4*)M3n)[bo] = mn[2];
    }
}

// ---------------------------------------------------------------------------
extern "C" void kernel_launch(void* const* d_in, const int* in_sizes, int n_in,
                              void* d_out, int out_size, void* d_ws, size_t ws_size,
                              hipStream_t stream) {
    const float* W1     = (const float*)d_in[0];
    const float* W2     = (const float*)d_in[1];
    const float* W3     = (const float*)d_in[2];
    const float* M1     = (const float*)d_in[3];
    const float* M2     = (const float*)d_in[4];
    const float* M3     = (const float*)d_in[5];
    const float* Ebase  = (const float*)d_in[6];
    const float* state  = (const float*)d_in[7];
    const float* outp   = (const float*)d_in[8];
    const float* A_in   = (const float*)d_in[9];
    const float* stepc  = (const float*)d_in[10];
    const float* eye    = (const float*)d_in[11];
    const float* stom   = (const float*)d_in[12];

    float* out = (float*)d_out;
    float* pred    = out;
    float* target  = out + ND;
    float* Anew    = out + 2 * ND;
    float* EbOut   = out + 2 * ND + NA;
    float* W1n     = out + 3 * ND + NA;
    float* W2n     = W1n + NW;
    float* W3n     = W2n + NW;
    float* M1n     = W3n + NW;
    float* M2n     = M1n + NW;
    float* M3n     = M2n + NW;
    float* counter_out = M3n + NW;       // final scalar

    float* ws = (float*)d_ws;
    float* q_ws = ws;
    float* k_ws = ws + ND;

    k_fused<<<NNODE * 3, 256, 0, stream>>>(
        W1, W2, W3, M1, M2, M3, state,
        pred, q_ws, k_ws, W1n, W2n, W3n, M1n, M2n, M3n);
    k_route_fix<<<NNODE, 128, 0, stream>>>(
        q_ws, k_ws, A_in, outp, eye, stom, pred, Ebase, stepc, state,
        W1, W2, W3, M1, M2, M3,
        target, Anew, EbOut, W1n, W2n, W3n, M1n, M2n, M3n, counter_out);
}

// Round 5
// 149.975 us; speedup vs baseline: 1.2767x; 1.0666x over previous
//
#include <hip/hip_runtime.h>
#include <hip/hip_bf16.h>
#include <math.h>

// Problem constants
#define BB 8
#define NN 80
#define DD 128
#define NNODE (BB*NN)            // 640
#define ND (NNODE*DD)            // 81920
#define NA (BB*NN*NN)            // 51200
#define NW ((size_t)NNODE*DD*DD) // 10,485,760

typedef float f4 __attribute__((ext_vector_type(4)));

__device__ __forceinline__ float pred_nl(float v) {
    const float PHI_C = 1.61803398875f;
    const float PREDS = 1.8477590650225735f; // sqrt(2 + sqrt(2))
    float raw = v - tanhf(v) * PHI_C;
    return tanhf(raw) * PREDS;
}

// ---------------------------------------------------------------------------
// K1: fused GEMV + bulk update, one pass over W1-3/M1-3.
// blockIdx.x = node*2 + half (half = rows 0-63 / 64-127).
// Round-2-proven streaming shape: ROLLED loop (#pragma unroll 1), 6
// independent f4 loads -> compute -> 6 NT stores per iteration.
// Bulk update (g_mask==0 exactly, f32 underflow for diff>=2):
//   Mn = 0.42*M ; Wn = W + 0.001*Mn  — coef-independent.
// Center column groups get the same bulk store, then K2 overwrites them
// with the exact reference formula.
// GEMV: out[c] = sum_r s[r]*W[r][c]; per-thread partial over its 8 rows,
// LDS-reduce over 8 row-residues, raw half-partials -> ws.
// ---------------------------------------------------------------------------
__global__ __launch_bounds__(256) void k_fused(
    const float* __restrict__ W1, const float* __restrict__ W2,
    const float* __restrict__ W3, const float* __restrict__ M1,
    const float* __restrict__ M2, const float* __restrict__ M3,
    const float* __restrict__ state,
    f4* __restrict__ ws_raw,     // [mat][half][node][32] f4 partials
    float* __restrict__ W1n, float* __restrict__ W2n, float* __restrict__ W3n,
    float* __restrict__ M1n, float* __restrict__ M2n, float* __restrict__ M3n)
{
    int bid  = blockIdx.x;
    int node = bid >> 1;
    int half = bid & 1;
    size_t base4 = (size_t)node * 4096;          // f4 units per node-matrix
    const f4* W1v = (const f4*)W1 + base4;
    const f4* W2v = (const f4*)W2 + base4;
    const f4* W3v = (const f4*)W3 + base4;
    const f4* M1v = (const f4*)M1 + base4;
    const f4* M2v = (const f4*)M2 + base4;
    const f4* M3v = (const f4*)M3 + base4;
    f4* W1nv = (f4*)W1n + base4;
    f4* W2nv = (f4*)W2n + base4;
    f4* W3nv = (f4*)W3n + base4;
    f4* M1nv = (f4*)M1n + base4;
    f4* M2nv = (f4*)M2n + base4;
    f4* M3nv = (f4*)M3n + base4;

    __shared__ __align__(16) float sv[DD];
    __shared__ f4 red[3 * 256];
    int t = threadIdx.x;
    if (t < DD) sv[t] = state[(size_t)node * DD + t];
    __syncthreads();

    int res = t >> 5;      // row residue 0..7
    int cg  = t & 31;      // f4 column group

    f4 acc1 = (f4)0.0f, acc2 = (f4)0.0f, acc3 = (f4)0.0f;
    #pragma unroll 1
    for (int u = 0; u < 8; ++u) {
        int r = half * 64 + u * 8 + res;
        size_t off = (size_t)r * 32 + cg;
        f4 w1 = W1v[off];
        f4 w2 = W2v[off];
        f4 w3 = W3v[off];
        f4 m1 = __builtin_nontemporal_load(M1v + off);
        f4 m2 = __builtin_nontemporal_load(M2v + off);
        f4 m3 = __builtin_nontemporal_load(M3v + off);
        float sj = sv[r];
        acc1.x = fmaf(sj, w1.x, acc1.x); acc1.y = fmaf(sj, w1.y, acc1.y);
        acc1.z = fmaf(sj, w1.z, acc1.z); acc1.w = fmaf(sj, w1.w, acc1.w);
        acc2.x = fmaf(sj, w2.x, acc2.x); acc2.y = fmaf(sj, w2.y, acc2.y);
        acc2.z = fmaf(sj, w2.z, acc2.z); acc2.w = fmaf(sj, w2.w, acc2.w);
        acc3.x = fmaf(sj, w3.x, acc3.x); acc3.y = fmaf(sj, w3.y, acc3.y);
        acc3.z = fmaf(sj, w3.z, acc3.z); acc3.w = fmaf(sj, w3.w, acc3.w);
        f4 n1 = 0.42f * m1, n2 = 0.42f * m2, n3 = 0.42f * m3;
        f4 o1 = w1 + 0.001f * n1, o2 = w2 + 0.001f * n2, o3 = w3 + 0.001f * n3;
        __builtin_nontemporal_store(n1, M1nv + off);
        __builtin_nontemporal_store(n2, M2nv + off);
        __builtin_nontemporal_store(n3, M3nv + off);
        __builtin_nontemporal_store(o1, W1nv + off);
        __builtin_nontemporal_store(o2, W2nv + off);
        __builtin_nontemporal_store(o3, W3nv + off);
    }
    red[t]       = acc1;
    red[256 + t] = acc2;
    red[512 + t] = acc3;
    __syncthreads();
    if (t < 96) {
        int mat = t >> 5;
        int cgg = t & 31;
        f4 r = red[mat * 256 + cgg];
        #pragma unroll
        for (int p = 1; p < 8; ++p) r += red[mat * 256 + p * 32 + cgg];
        ws_raw[((size_t)(mat * 2 + half) * NNODE + node) * 32 + cgg] = r;
    }
}

// ---------------------------------------------------------------------------
// K2: combine GEMV halves (pred/keys/queries), routing + softmax chain ->
// coef, then exact update of the center column groups (overwrites K1's bulk
// values there; full-f4 stores). One block of 128 per node; t = row i.
// ---------------------------------------------------------------------------
__global__ __launch_bounds__(128) void k_route_fix(
    const float* __restrict__ ws_raw_f,
    const float* __restrict__ A_in, const float* __restrict__ outp,
    const float* __restrict__ eye, const float* __restrict__ stomach,
    const float* __restrict__ Ebase,
    const float* __restrict__ stepc, const float* __restrict__ state,
    const float* __restrict__ W1, const float* __restrict__ W2,
    const float* __restrict__ W3, const float* __restrict__ M1,
    const float* __restrict__ M2, const float* __restrict__ M3,
    float* __restrict__ pred_out,
    float* __restrict__ target, float* __restrict__ Anew,
    float* __restrict__ EbOut,
    float* __restrict__ W1n, float* __restrict__ W2n, float* __restrict__ W3n,
    float* __restrict__ M1n, float* __restrict__ M2n, float* __restrict__ M3n,
    float* __restrict__ counter_out)
{
    int node = blockIdx.x;        // b*NN + n
    int b = node / NN;
    int n = node - b * NN;
    int t = threadIdx.x;
    int lane = t & 63;
    int wv = t >> 6;              // wave id (0 or 1)

    __shared__ __align__(16) float q_l[DD];
    __shared__ float raw[NN];
    __shared__ float a_l[NN];
    __shared__ int   idx5[5];
    __shared__ float p5[5];
    __shared__ float redbuf[2];

    const float* rawp0 = ws_raw_f + (size_t)0 * NNODE * DD;
    const float* rawp1 = ws_raw_f + (size_t)1 * NNODE * DD;
    const float* rawk0 = ws_raw_f + (size_t)2 * NNODE * DD;
    const float* rawk1 = ws_raw_f + (size_t)3 * NNODE * DD;
    const float* rawq0 = ws_raw_f + (size_t)4 * NNODE * DD;
    const float* rawq1 = ws_raw_f + (size_t)5 * NNODE * DD;

    // early-issue loads: center-group W/M (latency hides under routing)
    float counter = stepc[0] + 1.0f;
    float center  = fmodf(counter * 1.5f, 128.0f);
    int c0 = (int)floorf(center);
    int g0 = ((c0 - 1) & 127) >> 2;
    int g1 = ((c0 + 2) & 127) >> 2;
    size_t rb = (size_t)node * 4096 + (size_t)t * 32;
    f4 wA[3], mA[3], wB[3], mB[3];
    {
        const f4* Ws0 = (const f4*)W1; const f4* Ws1 = (const f4*)W2; const f4* Ws2 = (const f4*)W3;
        const f4* Ms0 = (const f4*)M1; const f4* Ms1 = (const f4*)M2; const f4* Ms2 = (const f4*)M3;
        wA[0] = Ws0[rb + g0]; wA[1] = Ws1[rb + g0]; wA[2] = Ws2[rb + g0];
        mA[0] = Ms0[rb + g0]; mA[1] = Ms1[rb + g0]; mA[2] = Ms2[rb + g0];
        wB[0] = Ws0[rb + g1]; wB[1] = Ws1[rb + g1]; wB[2] = Ws2[rb + g1];
        mB[0] = Ms0[rb + g1]; mB[1] = Ms1[rb + g1]; mB[2] = Ms2[rb + g1];
    }

    // combine halves: queries -> LDS, prediction -> register + global
    q_l[t] = rawq0[(size_t)node * DD + t] + rawq1[(size_t)node * DD + t];
    float praw = rawp0[(size_t)node * DD + t] + rawp1[(size_t)node * DD + t];
    float pred_v = pred_nl(praw);
    pred_out[(size_t)node * DD + t] = pred_v;
    __syncthreads();

    // raw_A[n,m] = dot(q_n, k_m) / sqrt(D)
    for (int m = wv; m < NN; m += 2) {
        size_t kb = (size_t)(b * NN + m) * DD;
        float klo = rawk0[kb + lane] + rawk1[kb + lane];
        float khi = rawk0[kb + lane + 64] + rawk1[kb + lane + 64];
        float p = q_l[lane] * klo + q_l[lane + 64] * khi;
        #pragma unroll
        for (int off = 32; off > 0; off >>= 1) p += __shfl_xor(p, off);
        if (lane == 0) raw[m] = p * 0.08838834764831845f; // 1/sqrt(128)
    }
    __syncthreads();

    // top-5 + softmax (serial, tiny; lax.top_k tie semantics: strict >)
    if (t == 0) {
        float vals[5]; int ids[5];
        for (int p = 0; p < 5; ++p) {
            float best = -INFINITY; int bi = 0;
            for (int m = 0; m < NN; ++m) {
                bool skip = false;
                for (int q = 0; q < p; ++q) if (ids[q] == m) skip = true;
                if (skip) continue;
                float v = raw[m];
                if (v > best) { best = v; bi = m; }
            }
            vals[p] = best; ids[p] = bi;
        }
        float mx = vals[0], s = 0.f, e[5];
        for (int p = 0; p < 5; ++p) { e[p] = expf(vals[p] - mx); s += e[p]; }
        for (int p = 0; p < 5; ++p) { p5[p] = e[p] / s; idx5[p] = ids[p]; }
    }
    __syncthreads();

    // A_new = 0.99*A + 0.01*P; rows 0,1 zeroed
    if (t < NN) {
        float P = 0.f;
        #pragma unroll
        for (int q = 0; q < 5; ++q) if (idx5[q] == t) P = p5[q];
        float a = A_in[(size_t)b * NN * NN + (size_t)n * NN + t] * 0.99f + P * 0.01f;
        if (n < 2) a = 0.f;
        a_l[t] = a;
        Anew[(size_t)b * NN * NN + (size_t)n * NN + t] = a;
    }
    __syncthreads();

    // target = A_new-weighted message aggregation (rows 0/1 -> env)
    float tg = 0.f;
    for (int m = 0; m < NN; ++m)
        tg = fmaf(a_l[m], outp[(size_t)(b * NN + m) * DD + t], tg);
    if (n == 0) tg = eye[b * DD + t];
    else if (n == 1) tg = stomach[b * DD + t];

    float err = pred_v - tg;

    // softmax over D=128 (2 waves)
    float v = err;
    #pragma unroll
    for (int off = 32; off > 0; off >>= 1) v = fmaxf(v, __shfl_xor(v, off));
    if (lane == 0) redbuf[wv] = v;
    __syncthreads();
    float mx = fmaxf(redbuf[0], redbuf[1]);
    __syncthreads();          // before redbuf reuse
    float e = expf(err - mx);
    v = e;
    #pragma unroll
    for (int off = 32; off > 0; off >>= 1) v += __shfl_xor(v, off);
    if (lane == 0) redbuf[wv] = v;
    __syncthreads();
    float Ecur = e / (redbuf[0] + redbuf[1]);

    float ebin = Ebase[(size_t)node * DD + t];
    float eb0  = (ebin == 0.f) ? Ecur : ebin;
    float EbV  = 0.5f * eb0 + 0.5f * Ecur;
    float adv  = Ecur - EbV;
    float R    = -(adv * (1.0f / sqrtf(adv * adv + 1e-8f))); // rms_norm, size-1 axis
    float plast = 1.f - R;
    float maskp = (EbV > 0.f) ? 1.f : 0.f;
    float coef  = -plast * err * maskp;   // hebb[i][j] = coef_i * state_j

    target[(size_t)node * DD + t] = tg;
    EbOut [(size_t)node * DD + t] = EbV;
    if (node == 0 && t == 0) counter_out[0] = counter;

    // ---- fix phase: exact update of center column groups, row i = t ----
    int nslot = (g1 == g0) ? 1 : 2;
    for (int sg = 0; sg < nslot; ++sg) {
        int g = (sg == 0) ? g0 : g1;
        f4 *wp = (sg == 0) ? wA : wB;
        f4 *mp = (sg == 0) ? mA : mB;
        f4 wn[3], mn[3];
        #pragma unroll
        for (int d = 0; d < 4; ++d) {
            int c = 4 * g + d;
            float diff = fabsf((float)c - center);
            diff = fminf(diff, 128.0f - diff);
            float gm = expf(-diff * diff / 0.020001f);   // 2*0.1^2 + 1e-6
            float hebb = coef * state[(size_t)node * DD + c];
            #pragma unroll
            for (int mat = 0; mat < 3; ++mat) {
                int prev = (mat == 0) ? 2 : mat - 1;     // grad1<-W3, grad2<-W1, grad3<-W2
                float grad = (hebb + 0.01f * wp[prev][d] - 0.01f * wp[mat][d]) * gm;
                float mval = 0.42f * mp[mat][d] + 0.58f * grad;
                mn[mat][d] = mval;
                wn[mat][d] = wp[mat][d] + 0.001f * mval;
            }
        }
        size_t bo = rb + g;
        ((f4*)W1n)[bo] = wn[0]; ((f4*)W2n)[bo] = wn[1]; ((f4*)W3n)[bo] = wn[2];
        ((f4*)M1n)[bo] = mn[0]; ((f4*)M2n)[bo] = mn[1]; ((f4*)M3n)[bo] = mn[2];
    }
}

// ---------------------------------------------------------------------------
extern "C" void kernel_launch(void* const* d_in, const int* in_sizes, int n_in,
                              void* d_out, int out_size, void* d_ws, size_t ws_size,
                              hipStream_t stream) {
    const float* W1     = (const float*)d_in[0];
    const float* W2     = (const float*)d_in[1];
    const float* W3     = (const float*)d_in[2];
    const float* M1     = (const float*)d_in[3];
    const float* M2     = (const float*)d_in[4];
    const float* M3     = (const float*)d_in[5];
    const float* Ebase  = (const float*)d_in[6];
    const float* state  = (const float*)d_in[7];
    const float* outp   = (const float*)d_in[8];
    const float* A_in   = (const float*)d_in[9];
    const float* stepc  = (const float*)d_in[10];
    const float* eye    = (const float*)d_in[11];
    const float* stom   = (const float*)d_in[12];

    float* out = (float*)d_out;
    float* pred    = out;
    float* target  = out + ND;
    float* Anew    = out + 2 * ND;
    float* EbOut   = out + 2 * ND + NA;
    float* W1n     = out + 3 * ND + NA;
    float* W2n     = W1n + NW;
    float* W3n     = W2n + NW;
    float* M1n     = W3n + NW;
    float* M2n     = M1n + NW;
    float* M3n     = M2n + NW;
    float* counter_out = M3n + NW;       // final scalar

    // ws: raw GEMV partials [3 mats][2 halves][640 nodes][128] floats = 1.97MB
    f4* ws_raw = (f4*)d_ws;

    k_fused<<<NNODE * 2, 256, 0, stream>>>(
        W1, W2, W3, M1, M2, M3, state, ws_raw,
        W1n, W2n, W3n, M1n, M2n, M3n);
    k_route_fix<<<NNODE, 128, 0, stream>>>(
        (const float*)d_ws, A_in, outp, eye, stom, Ebase, stepc, state,
        W1, W2, W3, M1, M2, M3,
        pred, target, Anew, EbOut, W1n, W2n, W3n, M1n, M2n, M3n, counter_out);
}